// Round 2
// baseline (213.022 us; speedup 1.0000x reference)
//
#include <hip/hip_runtime.h>

// LinearTextEmbedding: out[c][x][y] = (|bits[(x*1024+y) % 4096]| > 0.5) ? 1 : 0
// broadcast over 48 channels. Flat: out[o] = f(bits[o & 4095]) since both the
// image size (1048576) and channel stride are multiples of 4096.
//
// Pure write-bandwidth problem: 201.3 MB out, 16 KB in.
//
// Key structure: the output is PERIODIC with period 4096 floats (1024 float4).
// A thread that strides by a multiple of 1024 float4s sees a constant bit
// index, so it loads `bits` once, computes its float4 once, and then issues
// a pure stream of independent coalesced stores — max store ILP, no per-store
// load dependency, and only one occupancy generation of waves (2048 blocks).

// native clang vector type: __builtin_nontemporal_store rejects the
// HIP_vector_type<float,4> struct but accepts ext_vector_type.
typedef float f4 __attribute__((ext_vector_type(4)));

#define OUT_ELEMS (48u * 1024u * 1024u)   // 50331648 floats
#define N4        (OUT_ELEMS / 4u)        // 12582912 float4 stores
#define BLOCK     256u
#define GRID      2048u                   // 8 blocks/CU * 256 CUs -> full occupancy
#define NTHREADS  (BLOCK * GRID)          // 524288 threads
#define ITERS     (N4 / NTHREADS)         // 24 stores/thread, exact (no tail)

// stride check: NTHREADS % 1024 == 0 -> (t + k*NTHREADS) & 1023 == t & 1023,
// so the float4 of `bits` this thread needs is invariant across k.
static_assert(NTHREADS % 1024u == 0u, "stride must preserve bit index");
static_assert(ITERS * NTHREADS == N4, "exact cover, no tail");

__global__ __launch_bounds__(BLOCK) void
LinearTextEmbedding_57604101374655_kernel(const float* __restrict__ bits,
                                          f4* __restrict__ out) {
    unsigned t = blockIdx.x * BLOCK + threadIdx.x;
    // bit index for the 4 floats this thread writes: (t*4) & 4095, aligned to 4,
    // never straddles the 4096 wrap -> single float4 load at index t & 1023.
    f4 b = reinterpret_cast<const f4*>(bits)[t & 1023u];
    f4 v;
    v.x = (fabsf(b.x) > 0.5f) ? 1.0f : 0.0f;
    v.y = (fabsf(b.y) > 0.5f) ? 1.0f : 0.0f;
    v.z = (fabsf(b.z) > 0.5f) ? 1.0f : 0.0f;
    v.w = (fabsf(b.w) > 0.5f) ? 1.0f : 0.0f;

    f4* p = out + t;
#pragma unroll
    for (unsigned k = 0; k < ITERS; ++k) {
        __builtin_nontemporal_store(v, p);   // streaming store, no L2 pollution
        p += NTHREADS;                       // 8 MB stride, coalesced per wave
    }
}

extern "C" void kernel_launch(void* const* d_in, const int* in_sizes, int n_in,
                              void* d_out, int out_size, void* d_ws, size_t ws_size,
                              hipStream_t stream) {
    const float* bits = (const float*)d_in[0];
    f4* out = (f4*)d_out;
    LinearTextEmbedding_57604101374655_kernel<<<GRID, BLOCK, 0, stream>>>(bits, out);
}

// Round 3
// 195.854 us; speedup vs baseline: 1.0877x; 1.0877x over previous
//
#include <hip/hip_runtime.h>

// LinearTextEmbedding: out[c][x][y] = (|bits[(x*1024+y) % 4096]| > 0.5) ? 1 : 0
// broadcast over 48 channels. Flat: out[o] = f(bits[o & 4095]) since both the
// image size (1048576) and channel stride are multiples of 4096.
//
// Pure write-bandwidth problem: 201.3 MB out, 16 KB in.
//
// Structure: output is PERIODIC with period 4096 floats (1024 float4). A
// thread striding by a multiple of 1024 float4s has a constant bit index:
// load `bits` once, compute once, then a pure stream of 24 independent
// coalesced stores (1 KB/wave/instruction, 8 MB apart).
//
// Round-2 lesson: __builtin_nontemporal_store (evict-first) regressed ~35%
// vs plain stores — it defeats L2/L3 write-combining, sending isolated
// 256 B writes to HBM. The rocclr fill kernel hits 6.4 TB/s at 9% occupancy
// with plain batched stores; do the same.

typedef float f4 __attribute__((ext_vector_type(4)));

#define OUT_ELEMS (48u * 1024u * 1024u)   // 50331648 floats
#define N4        (OUT_ELEMS / 4u)        // 12582912 float4 stores
#define BLOCK     256u
#define GRID      2048u                   // 8 blocks/CU * 256 CUs
#define NTHREADS  (BLOCK * GRID)          // 524288 threads
#define ITERS     (N4 / NTHREADS)         // 24 stores/thread, exact (no tail)

// stride check: NTHREADS % 1024 == 0 -> (t + k*NTHREADS) & 1023 == t & 1023,
// so the float4 of `bits` this thread needs is invariant across k.
static_assert(NTHREADS % 1024u == 0u, "stride must preserve bit index");
static_assert(ITERS * NTHREADS == N4, "exact cover, no tail");

__global__ __launch_bounds__(BLOCK) void
LinearTextEmbedding_57604101374655_kernel(const float* __restrict__ bits,
                                          f4* __restrict__ out) {
    unsigned t = blockIdx.x * BLOCK + threadIdx.x;
    // bit index for the 4 floats this thread writes: (t*4) & 4095, aligned to 4,
    // never straddles the 4096 wrap -> single float4 load at index t & 1023.
    f4 b = reinterpret_cast<const f4*>(bits)[t & 1023u];
    f4 v;
    v.x = (fabsf(b.x) > 0.5f) ? 1.0f : 0.0f;
    v.y = (fabsf(b.y) > 0.5f) ? 1.0f : 0.0f;
    v.z = (fabsf(b.z) > 0.5f) ? 1.0f : 0.0f;
    v.w = (fabsf(b.w) > 0.5f) ? 1.0f : 0.0f;

    f4* p = out + t;
#pragma unroll
    for (unsigned k = 0; k < ITERS; ++k) {
        *p = v;                              // plain store: L2/L3 write-combining
        p += NTHREADS;                       // 8 MB stride, coalesced per wave
    }
}

extern "C" void kernel_launch(void* const* d_in, const int* in_sizes, int n_in,
                              void* d_out, int out_size, void* d_ws, size_t ws_size,
                              hipStream_t stream) {
    const float* bits = (const float*)d_in[0];
    f4* out = (f4*)d_out;
    LinearTextEmbedding_57604101374655_kernel<<<GRID, BLOCK, 0, stream>>>(bits, out);
}

// Round 6
// 191.708 us; speedup vs baseline: 1.1112x; 1.0216x over previous
//
#include <hip/hip_runtime.h>

// LinearTextEmbedding: out[c][x][y] = (|bits[(x*1024+y) % 4096]| > 0.5) ? 1 : 0
// broadcast over 48 channels. Flat: out[o] = f(bits[o & 4095]) since both the
// image size (1048576) and channel stride are multiples of 4096.
//
// Pure write-bandwidth problem: 201.3 MB out, 16 KB in.
//
// Round-2 lesson: nontemporal stores regress ~35% (defeat L2 write batching).
// Round-3 lesson: 8 MB-stride grid-stride walk regresses vs an ordered sweep
//   (dirty lines spread over the whole 201 MB in all 8 L2s -> random-order
//   eviction to DRAM). Address order over time matters for write streams.
//
// This version: contiguous-per-block sweep + store ILP.
//   Block b owns float4s [b*6144, (b+1)*6144) -- a contiguous 96 KB segment
//   that is exactly 6 periods of the 4096-float bit pattern. Iteration k
//   stores a contiguous 4 KB wave chunk at base + k*256 + t. The bit index
//   depends only on k&3, so each thread precomputes 4 result vectors from
//   4 L1-resident bits loads, then issues 24 independent in-order stores.

typedef float f4 __attribute__((ext_vector_type(4)));

#define OUT_ELEMS (48u * 1024u * 1024u)   // 50331648 floats
#define N4        (OUT_ELEMS / 4u)        // 12582912 float4 stores
#define BLOCK     256u
#define ITERS     24u                     // stores per thread
#define SEG       (BLOCK * ITERS)         // 6144 float4s = 96 KB per block
#define GRID      (N4 / SEG)              // 2048 blocks = 8 per CU, one generation

static_assert(GRID * SEG == N4, "exact cover, no tail");
static_assert((SEG * 4u) % 4096u == 0u, "block segment = whole periods");
static_assert((BLOCK * 4u * 4u) == 4096u, "4 iters span one period (k&3)");

__global__ __launch_bounds__(BLOCK) void
LinearTextEmbedding_57604101374655_kernel(const float* __restrict__ bits,
                                          f4* __restrict__ out) {
    unsigned t = threadIdx.x;
    unsigned base = blockIdx.x * SEG;

    // float offset within a block segment for iter k, lane t: 1024*k + 4*t.
    // mod 4096 -> depends only on k&3: bits float4 index (t + 256*(k&3)) & 1023.
    const f4* b4 = reinterpret_cast<const f4*>(bits);
    f4 v[4];
#pragma unroll
    for (unsigned j = 0; j < 4; ++j) {
        f4 b = b4[(t + 256u * j) & 1023u];
        v[j].x = (fabsf(b.x) > 0.5f) ? 1.0f : 0.0f;
        v[j].y = (fabsf(b.y) > 0.5f) ? 1.0f : 0.0f;
        v[j].z = (fabsf(b.z) > 0.5f) ? 1.0f : 0.0f;
        v[j].w = (fabsf(b.w) > 0.5f) ? 1.0f : 0.0f;
    }

    f4* p = out + base + t;
#pragma unroll
    for (unsigned k = 0; k < ITERS; ++k) {
        p[k * BLOCK] = v[k & 3u];   // contiguous 4 KB/wave/iter, ordered sweep
    }
}

extern "C" void kernel_launch(void* const* d_in, const int* in_sizes, int n_in,
                              void* d_out, int out_size, void* d_ws, size_t ws_size,
                              hipStream_t stream) {
    const float* bits = (const float*)d_in[0];
    f4* out = (f4*)d_out;
    LinearTextEmbedding_57604101374655_kernel<<<GRID, BLOCK, 0, stream>>>(bits, out);
}